// Round 10
// baseline (114.938 us; speedup 1.0000x reference)
//
#include <hip/hip_runtime.h>

#define BB 16
#define SS 2048
#define DD 64
#define L2E 1.44269504f
#define A3C 4.32808512f   // 3 * log2(e)

typedef _Float16 half8 __attribute__((ext_vector_type(8)));
typedef _Float16 half4 __attribute__((ext_vector_type(4)));
typedef float f32x4 __attribute__((ext_vector_type(4)));

typedef const __attribute__((address_space(1))) void* gas_ptr;
typedef __attribute__((address_space(3))) void* las_ptr;

// per-wave counted vmem wait (no barrier); sched_barrier stops ds_read hoisting
#define WAITV(N)                                                \
  do {                                                          \
    asm volatile("s_waitcnt vmcnt(" #N ")" ::: "memory");       \
    __builtin_amdgcn_sched_barrier(0);                          \
  } while (0)

// ---------------- setup: K -> f16 copy, V -> f16 transposed [b][d][s] ----------------
__global__ __launch_bounds__(256) void setup_kernel(const float* __restrict__ K,
                                                    const float* __restrict__ V,
                                                    _Float16* __restrict__ Kh,
                                                    _Float16* __restrict__ VT) {
  __shared__ float tile[64][65];
  int b = blockIdx.x >> 5, kt = blockIdx.x & 31;  // 32 tiles of 64 rows
  int tid = threadIdx.x;
  size_t base = ((size_t)b * SS + (size_t)kt * 64) * DD;
  const float4* Kq = (const float4*)(K + base);
  const float4* Vq = (const float4*)(V + base);
  half4* Khq = (half4*)(Kh + base);
#pragma unroll
  for (int it = 0; it < 4; ++it) {
    int i = tid + it * 256;  // quad index 0..1023 over 64x64 tile
    float4 kv = Kq[i];
    half4 h;
    h[0] = (_Float16)kv.x; h[1] = (_Float16)kv.y;
    h[2] = (_Float16)kv.z; h[3] = (_Float16)kv.w;
    Khq[i] = h;
    float4 vv = Vq[i];
    int row = i >> 4, c4 = (i & 15) << 2;
    tile[row][c4 + 0] = vv.x; tile[row][c4 + 1] = vv.y;
    tile[row][c4 + 2] = vv.z; tile[row][c4 + 3] = vv.w;
  }
  __syncthreads();
  int d = tid >> 2, seg = tid & 3;  // 64 d-rows x 4 segments of 16 k
  half8 o0, o1;
#pragma unroll
  for (int j = 0; j < 8; ++j) o0[j] = (_Float16)tile[seg * 16 + j][d];
#pragma unroll
  for (int j = 0; j < 8; ++j) o1[j] = (_Float16)tile[seg * 16 + 8 + j][d];
  _Float16* dst = VT + ((size_t)b * DD + d) * SS + (size_t)kt * 64 + seg * 16;
  *(half8*)dst = o0;
  *(half8*)(dst + 8) = o1;
}

// Stage a 32-key K tile [32 rows][128B] into a per-wave LDS slot, XOR-swizzled
// on the global source (global_load_lds writes lane-linear). 4 x 16B per lane.
__device__ __forceinline__ void stageK32(const _Float16* __restrict__ kb,
                                         _Float16* lds, int lam) {
#pragma unroll
  for (int a = 0; a < 4; ++a) {
    int rloc = lam >> 3;                              // 0..7 (== row & 7)
    int r = a * 8 + rloc;
    int byt = ((lam & 7) * 16) ^ (rloc << 4);
    __builtin_amdgcn_global_load_lds((gas_ptr)(kb + (size_t)r * DD + (byt >> 1)),
                                     (las_ptr)(lds + a * 512), 16, 0, 0);
  }
}

// Stage a 32-key V tile, kt-major [2 kt][64 d][16 halfs], linear. 4 x 16B per lane.
__device__ __forceinline__ void stageV32(const _Float16* __restrict__ vb,
                                         _Float16* lds, int lam) {
#pragma unroll
  for (int a = 0; a < 4; ++a) {
    int kt = a >> 1;
    int d = (a & 1) * 32 + (lam >> 1);
    int h = lam & 1;
    __builtin_amdgcn_global_load_lds((gas_ptr)(vb + (size_t)d * SS + kt * 16 + h * 8),
                                     (las_ptr)(lds + a * 512), 16, 0, 0);
  }
}

__device__ __forceinline__ void load_qfrag(const float* __restrict__ Qp,
                                           half8& qa0, half8& qa1) {
  float4 v0 = *(const float4*)(Qp);
  float4 v1 = *(const float4*)(Qp + 4);
  float4 v2 = *(const float4*)(Qp + 32);
  float4 v3 = *(const float4*)(Qp + 36);
  qa0[0] = (_Float16)(v0.x * 0.125f); qa0[1] = (_Float16)(v0.y * 0.125f);
  qa0[2] = (_Float16)(v0.z * 0.125f); qa0[3] = (_Float16)(v0.w * 0.125f);
  qa0[4] = (_Float16)(v1.x * 0.125f); qa0[5] = (_Float16)(v1.y * 0.125f);
  qa0[6] = (_Float16)(v1.z * 0.125f); qa0[7] = (_Float16)(v1.w * 0.125f);
  qa1[0] = (_Float16)(v2.x * 0.125f); qa1[1] = (_Float16)(v2.y * 0.125f);
  qa1[2] = (_Float16)(v2.z * 0.125f); qa1[3] = (_Float16)(v2.w * 0.125f);
  qa1[4] = (_Float16)(v3.x * 0.125f); qa1[5] = (_Float16)(v3.y * 0.125f);
  qa1[6] = (_Float16)(v3.z * 0.125f); qa1[7] = (_Float16)(v3.w * 0.125f);
}

// ---------------- fused attention: barrier-free, per-wave private tiles ----------------
// wg = 4 waves x 16 q-rows; each wave sweeps ALL k in private 32-key tiles.
// Swapped QK^T: s = mfma(K_frag, Q_frag) -> lane (g,c) holds S[q=qr+c][k=..+4g+j].
__global__ __launch_bounds__(256, 2) void attn_kernel(const float* __restrict__ Q,
                                                      const _Float16* __restrict__ Kh,
                                                      const _Float16* __restrict__ VT,
                                                      float* __restrict__ ctx_out,
                                                      float* __restrict__ attn_out) {
  __shared__ __attribute__((aligned(16))) _Float16 buf[4][4][2048];  // [wave][slot][4KB]

  int tid = threadIdx.x;
  int w = tid >> 6, l = tid & 63, g = l >> 4, c = l & 15;
  int bid = (int)blockIdx.x;
  int remap = (bid & 7) * 64 + (bid >> 3);   // XCD-contiguous (512 grid)
  int b = remap >> 5, qb = remap & 31;
  size_t qr = (size_t)b * SS + (size_t)qb * 64 + (size_t)w * 16;
  const _Float16* KB = Kh + (size_t)b * SS * DD;
  const _Float16* VB = VT + (size_t)b * DD * SS;
  _Float16* WB = &buf[w][0][0];              // 4 per-wave slots of 2048 halfs
  int swz = (c & 7) << 4;

  // Q first so the compiler's Q-wait doesn't drain the stage queue
  half8 qa0, qa1;
  load_qfrag(Q + (qr + c) * DD + 8 * g, qa0, qa1);

  // ---- sweep 1: row sums of exp(s - 3); K quad-buffered, prefetch depth 3 ----
  stageK32(KB, WB, l);
  stageK32(KB + (size_t)32 * DD, WB + 2048, l);
  stageK32(KB + (size_t)64 * DD, WB + 2 * 2048, l);

  float lsum = 0.f;
  for (int t = 0; t < 64; ++t) {
    if (t < 62) WAITV(8);
    else if (t == 62) WAITV(4);
    else WAITV(0);
    const _Float16* kl = WB + (t & 3) * 2048;
#pragma unroll
    for (int kt = 0; kt < 2; ++kt) {
      const _Float16* kb2 = kl + (kt * 16 + c) * 64;
      half8 kf0 = *(const half8*)(kb2 + (((16 * g) ^ swz) >> 1));
      half8 kf1 = *(const half8*)(kb2 + (((64 + 16 * g) ^ swz) >> 1));
      f32x4 s = {0.f, 0.f, 0.f, 0.f};
      s = __builtin_amdgcn_mfma_f32_16x16x32_f16(kf0, qa0, s, 0, 0, 0);
      s = __builtin_amdgcn_mfma_f32_16x16x32_f16(kf1, qa1, s, 0, 0, 0);
      lsum += exp2f(fmaf(s[0], L2E, -A3C)) + exp2f(fmaf(s[1], L2E, -A3C)) +
              exp2f(fmaf(s[2], L2E, -A3C)) + exp2f(fmaf(s[3], L2E, -A3C));
    }
    if (t < 61) {
      __builtin_amdgcn_sched_barrier(0);
      stageK32(KB + (size_t)(t + 3) * 32 * DD, WB + ((t + 3) & 3) * 2048, l);
    }
  }
  lsum += __shfl_xor(lsum, 16);
  lsum += __shfl_xor(lsum, 32);
  float ac = -__log2f(lsum) - A3C;  // p/l = exp2(s*L2E + ac)

  // ---- sweep 2: recompute S, write normalized attn, PV; K slots{0,1}, V slots{2,3} ----
  stageK32(KB, WB, l);
  stageV32(VB, WB + 2 * 2048, l);
  stageK32(KB + (size_t)32 * DD, WB + 2048, l);
  stageV32(VB + 32, WB + 3 * 2048, l);

  f32x4 cacc[4] = {{0.f, 0.f, 0.f, 0.f}, {0.f, 0.f, 0.f, 0.f},
                   {0.f, 0.f, 0.f, 0.f}, {0.f, 0.f, 0.f, 0.f}};
  for (int t = 0; t < 64; ++t) {
    if (t == 0) WAITV(8);
    else if (t < 63) WAITV(10);
    else WAITV(2);
    const _Float16* kl = WB + (t & 1) * 2048;
    const _Float16* vl = WB + (2 + (t & 1)) * 2048;
#pragma unroll
    for (int kt = 0; kt < 2; ++kt) {
      const _Float16* kb2 = kl + (kt * 16 + c) * 64;
      half8 kf0 = *(const half8*)(kb2 + (((16 * g) ^ swz) >> 1));
      half8 kf1 = *(const half8*)(kb2 + (((64 + 16 * g) ^ swz) >> 1));
      f32x4 s = {0.f, 0.f, 0.f, 0.f};
      s = __builtin_amdgcn_mfma_f32_16x16x32_f16(kf0, qa0, s, 0, 0, 0);
      s = __builtin_amdgcn_mfma_f32_16x16x32_f16(kf1, qa1, s, 0, 0, 0);

      float p0 = exp2f(fmaf(s[0], L2E, ac));
      float p1 = exp2f(fmaf(s[1], L2E, ac));
      float p2 = exp2f(fmaf(s[2], L2E, ac));
      float p3 = exp2f(fmaf(s[3], L2E, ac));
      float4 st = {p0, p1, p2, p3};
      *(float4*)(attn_out + (qr + c) * SS + t * 32 + kt * 16 + 4 * g) = st;

      half4 pf;
      pf[0] = (_Float16)p0; pf[1] = (_Float16)p1;
      pf[2] = (_Float16)p2; pf[3] = (_Float16)p3;
#pragma unroll
      for (int dt = 0; dt < 4; ++dt) {
        half4 vf = *(const half4*)(vl + kt * 1024 + (dt * 16 + c) * 16 + 4 * g);
        cacc[dt] = __builtin_amdgcn_mfma_f32_16x16x16f16(pf, vf, cacc[dt], 0, 0, 0);
      }
    }
    if (t < 62) {
      __builtin_amdgcn_sched_barrier(0);
      stageK32(KB + (size_t)(t + 2) * 32 * DD, WB + ((t + 2) & 1) * 2048, l);
      stageV32(VB + (size_t)(t + 2) * 32, WB + (2 + ((t + 2) & 1)) * 2048, l);
    }
  }

  // ---- ctx store (wave-local, fully reduced) ----
#pragma unroll
  for (int dt = 0; dt < 4; ++dt)
#pragma unroll
    for (int j = 0; j < 4; ++j)
      ctx_out[(qr + 4 * g + j) * DD + dt * 16 + c] = cacc[dt][j];
}

extern "C" void kernel_launch(void* const* d_in, const int* in_sizes, int n_in,
                              void* d_out, int out_size, void* d_ws, size_t ws_size,
                              hipStream_t stream) {
  const float* q = (const float*)d_in[0];
  const float* k = (const float*)d_in[1];
  const float* v = (const float*)d_in[2];
  float* ctx = (float*)d_out;
  float* attn = ctx + (size_t)BB * SS * DD;
  _Float16* Kh = (_Float16*)d_ws;                 // [B][S][D] f16, 4 MB
  _Float16* VT = Kh + (size_t)BB * SS * DD;       // [B][D][S] f16, 4 MB
  setup_kernel<<<dim3(BB * 32), dim3(256), 0, stream>>>(k, v, Kh, VT);
  attn_kernel<<<dim3(BB * 32), dim3(256), 0, stream>>>(q, Kh, VT, ctx, attn);
}